// Round 3
// baseline (522.482 us; speedup 1.0000x reference)
//
#include <hip/hip_runtime.h>
#include <limits.h>

#define HH 128
#define WW_ 128
#define HW 16384
#define NB 16
#define CF 192
#define H2 64
#define W2 64
#define RLCAP 4096

typedef float vf4 __attribute__((ext_vector_type(4)));
typedef unsigned long long ull;

// ---------------------------------------------------------------------------
// Union-find helpers (LDS parent array; nodes are run-start pixel ids).
// Links always go high->low index -> chains strictly decrease -> path halving
// under concurrency is safe and terminating.
// ---------------------------------------------------------------------------

__device__ inline int uf_find(int* par, int x) {
    volatile int* vp = (volatile int*)par;
    int p = vp[x];
    while (p != x) {
        int g = vp[p];
        vp[x] = g;      // path halving: writes an ancestor, safe under races
        x = g;
        p = vp[x];
    }
    return x;
}

__device__ inline void uf_union(int* par, int a, int b) {
    int ra = uf_find(par, a);
    int rb = uf_find(par, b);
    while (ra != rb) {
        if (ra < rb) { int t = ra; ra = rb; rb = t; }   // link larger -> smaller
        int old = atomicCAS(&par[ra], ra, rb);
        if (old == ra) return;
        ra = uf_find(par, old);
        rb = uf_find(par, rb);
    }
}

// ---------------------------------------------------------------------------
// 128-bit row mask helpers (lo = cols 0..63, hi = cols 64..127)
// ---------------------------------------------------------------------------

__device__ inline int getbit2(ull lo, ull hi, int c) {
    return (int)(((c < 64) ? (lo >> c) : (hi >> (c - 64))) & 1ULL);
}

__device__ inline int leading_ones(ull v) {
    ull nv = ~v;
    return (nv == 0ULL) ? 64 : __clzll(nv);
}

__device__ inline int trailing_ones(ull v) {
    ull nv = ~v;
    return (nv == 0ULL) ? 64 : (__ffsll(nv) - 1);
}

// column of the start of the fg run containing column c (bit c must be set)
__device__ inline int run_start_col(ull lo, ull hi, int c) {
    if (c < 64) {
        int ones = leading_ones(lo << (63 - c));   // consecutive ones ending at c
        return c - ones + 1;
    }
    int ones = leading_ones(hi << (127 - c));
    int rs = c - ones + 1;
    if (rs == 64) rs -= leading_ones(lo);          // run crosses the 64 boundary
    return rs;
}

// column of the end of the fg run containing column c (bit c must be set)
__device__ inline int run_end_col(ull lo, ull hi, int c) {
    if (c >= 64) {
        return c + trailing_ones(hi >> (c - 64)) - 1;
    }
    int e = c + trailing_ones(lo >> c) - 1;
    if (e == 63) e += trailing_ones(hi);           // run crosses the 64 boundary
    return e;
}

// ---------------------------------------------------------------------------
// Kernel 1: one block per image. Run-based union-find CCL with a hierarchical
// strip-merge schedule (round s merges boundaries r = s*(2k+1); disjoint
// strip pairs per round -> no cross-boundary CAS contention; flatten after
// each round keeps find chains <=2 hops). Then per-run stats with in-kernel
// init of root slots (no external memset needed).
// ---------------------------------------------------------------------------

__global__ __launch_bounds__(1024) void ccl_stats_kernel(
    const float* __restrict__ prob,
    int* __restrict__ cnt, float* __restrict__ conf,
    int* __restrict__ maxr, int* __restrict__ maxc, int* __restrict__ maxid,
    int* __restrict__ minr, int* __restrict__ minc,
    int* __restrict__ nroots, int* __restrict__ rootlist)
{
    __shared__ int parent[HW];
    __shared__ ull rowmask[HH][2];
    __shared__ int snroots;
    const int b = blockIdx.x;
    const int tid = threadIdx.x;
    const float* p = prob + (size_t)b * HW;
    const int base = b * HW;

    if (tid == 0) snroots = 0;

    // P0: per-row fg bitmasks. Each wave's 64 lanes cover half a row
    // (coalesced loads); ballot gives the 64-bit mask directly.
    #pragma unroll
    for (int k = 0; k < HW / 1024; ++k) {
        int i = k * 1024 + tid;
        bool fg = p[i] > 0.5f;
        ull m = __ballot(fg);
        if ((tid & 63) == 0) rowmask[i >> 7][(i >> 6) & 1] = m;
    }
    __syncthreads();

    // P1: parent self-init at run starts only
    #pragma unroll
    for (int k = 0; k < HW / 1024; ++k) {
        int i = k * 1024 + tid, r = i >> 7, c = i & 127;
        ull lo = rowmask[r][0], hi = rowmask[r][1];
        if (getbit2(lo, hi, c) && (c == 0 || !getbit2(lo, hi, c - 1)))
            parent[i] = i;
    }
    __syncthreads();

    // P2: hierarchical merge. Round s handles boundaries r = s*(2k+1),
    // k = 0..64/s-1 — each adjacent row pair processed exactly once, in the
    // round where the two strips first co-reside.
    for (int s = 1; s < HH; s <<= 1) {
        int nbound = 64 / s;
        int items = nbound * WW_;
        for (int it = tid; it < items; it += 1024) {
            int k = it >> 7;
            int c = it & 127;
            int r = s * (2 * k + 1);
            ull lo = rowmask[r][0], hi = rowmask[r][1];
            if (!getbit2(lo, hi, c)) continue;
            ull ulo = rowmask[r - 1][0], uhi = rowmask[r - 1][1];
            int l  = (c > 0)   ? getbit2(lo, hi, c - 1) : 0;
            int rt = (c < 127) ? getbit2(lo, hi, c + 1) : 0;
            int up = getbit2(ulo, uhi, c);
            int ul = (c > 0)   ? getbit2(ulo, uhi, c - 1) : 0;
            int ur = (c < 127) ? getbit2(ulo, uhi, c + 1) : 0;
            bool u1 = up && !(l && ul);          // leftmost contact dedup
            bool u2 = !up && ul && !l;
            bool u3 = !up && ur && !rt;
            if (u1 | u2 | u3) {
                int rs_i = (r << 7) + run_start_col(lo, hi, c);
                int ru = (r - 1) << 7;
                if (u1) uf_union(parent, rs_i, ru + run_start_col(ulo, uhi, c));
                if (u2) uf_union(parent, rs_i, ru + run_start_col(ulo, uhi, c - 1));
                if (u3) uf_union(parent, rs_i, ru + run_start_col(ulo, uhi, c + 1));
            }
        }
        __syncthreads();
        // flatten run starts -> keeps all subsequent finds <=2 hops
        for (int kk = 0; kk < HW / 1024; ++kk) {
            int i = kk * 1024 + tid, r = i >> 7, c = i & 127;
            ull lo = rowmask[r][0], hi = rowmask[r][1];
            if (getbit2(lo, hi, c) && (c == 0 || !getbit2(lo, hi, c - 1)))
                parent[i] = uf_find(parent, i);
        }
        __syncthreads();
    }

    // P3: roots init their own global stats slots + append to rootlist.
    // (in-kernel init replaces the 9 MB hipMemsetAsync pair)
    for (int k = 0; k < HW / 1024; ++k) {
        int i = k * 1024 + tid, r = i >> 7, c = i & 127;
        ull lo = rowmask[r][0], hi = rowmask[r][1];
        if (!(getbit2(lo, hi, c) && (c == 0 || !getbit2(lo, hi, c - 1)))) continue;
        if (parent[i] != i) continue;            // parents are flat: root test
        cnt[base + i] = 0;
        conf[base + i] = 0.f;
        minr[base + i] = INT_MAX;
        maxr[base + i] = -1;
        minc[base + i] = INT_MAX;
        maxc[base + i] = -1;
        maxid[base + i] = 0;                     // stored as idx+1
        int idx = atomicAdd(&snroots, 1);
        if (idx < RLCAP) rootlist[b * RLCAP + idx] = i;
    }
    __syncthreads();
    if (tid == 0) nroots[b] = snroots;

    // P4: per-run stats, one atomic flush per run.
    for (int k = 0; k < HW / 1024; ++k) {
        int i = k * 1024 + tid, r = i >> 7, c = i & 127;
        ull lo = rowmask[r][0], hi = rowmask[r][1];
        if (!(getbit2(lo, hi, c) && (c == 0 || !getbit2(lo, hi, c - 1)))) continue;
        int e = run_end_col(lo, hi, c);
        int root = parent[i];
        float s = 0.f;
        for (int j = c; j <= e; ++j) s += p[(r << 7) + j];
        atomicAdd(&cnt[base + root], e - c + 1);
        atomicAdd(&conf[base + root], s);
        atomicMin(&minr[base + root], r);
        atomicMax(&maxr[base + root], r);
        atomicMin(&minc[base + root], c);
        atomicMax(&maxc[base + root], e);
        atomicMax(&maxid[base + root], (r << 7) + e + 1);
    }
}

// ---------------------------------------------------------------------------
// Kernel 2: one block per image. Scan the compact root list, top-3 by
// (mean_conf desc, segment-id asc), K-dependent duplication, write 3 bboxes.
// ---------------------------------------------------------------------------

__global__ __launch_bounds__(256) void select_kernel(
    const int* __restrict__ cnt, const float* __restrict__ conf,
    const int* __restrict__ maxr, const int* __restrict__ maxc,
    const int* __restrict__ maxid,
    const int* __restrict__ minr, const int* __restrict__ minc,
    const int* __restrict__ nroots, const int* __restrict__ rootlist,
    int* __restrict__ bbox)
{
    const int b = blockIdx.x;
    const int tid = threadIdx.x;
    const int base = b * HW;
    int n = nroots[b];
    if (n > RLCAP) n = RLCAP;

    float s0 = -INFINITY, s1 = -INFINITY, s2 = -INFINITY;
    int id0 = INT_MAX, id1 = INT_MAX, id2 = INT_MAX;
    int r0 = -1, r1 = -1, r2 = -1;

    for (int i = tid; i < n; i += 256) {
        int rr = rootlist[b * RLCAP + i];
        int c = cnt[base + rr];
        float s = conf[base + rr] / (float)c;
        int id = maxid[base + rr];
        if (s > s0 || (s == s0 && id < id0)) {
            s2 = s1; id2 = id1; r2 = r1;
            s1 = s0; id1 = id0; r1 = r0;
            s0 = s; id0 = id; r0 = rr;
        } else if (s > s1 || (s == s1 && id < id1)) {
            s2 = s1; id2 = id1; r2 = r1;
            s1 = s; id1 = id; r1 = rr;
        } else if (s > s2 || (s == s2 && id < id2)) {
            s2 = s; id2 = id; r2 = rr;
        }
    }

    __shared__ float ss[256 * 3];
    __shared__ int sid[256 * 3];
    __shared__ int sr[256 * 3];
    ss[tid * 3 + 0] = s0; sid[tid * 3 + 0] = id0; sr[tid * 3 + 0] = r0;
    ss[tid * 3 + 1] = s1; sid[tid * 3 + 1] = id1; sr[tid * 3 + 1] = r1;
    ss[tid * 3 + 2] = s2; sid[tid * 3 + 2] = id2; sr[tid * 3 + 2] = r2;
    __syncthreads();

    if (tid == 0) {
        float t0 = -INFINITY, t1 = -INFINITY, t2 = -INFINITY;
        int tid0 = INT_MAX, tid1 = INT_MAX, tid2 = INT_MAX;
        int tr0 = -1, tr1 = -1, tr2 = -1;
        int lim = (n < 256 ? n : 256) * 3;
        for (int t = 0; t < lim; ++t) {
            float s = ss[t]; int id = sid[t]; int rr = sr[t];
            if (rr < 0) continue;
            if (s > t0 || (s == t0 && id < tid0)) {
                t2 = t1; tid2 = tid1; tr2 = tr1;
                t1 = t0; tid1 = tid0; tr1 = tr0;
                t0 = s; tid0 = id; tr0 = rr;
            } else if (s > t1 || (s == t1 && id < tid1)) {
                t2 = t1; tid2 = tid1; tr2 = tr1;
                t1 = s; tid1 = id; tr1 = rr;
            } else if (s > t2 || (s == t2 && id < tid2)) {
                t2 = s; tid2 = id; tr2 = rr;
            }
        }
        int K = n;
        int roots[3];
        if (K >= 3)      { roots[0] = tr0; roots[1] = tr1; roots[2] = tr2; }
        else if (K == 2) { roots[0] = tr0; roots[1] = tr0; roots[2] = tr1; }
        else             { roots[0] = tr0; roots[1] = tr0; roots[2] = tr0; }
        for (int slot = 0; slot < 3; ++slot) {
            int mr, h, mc, w;
            if (K == 0) { mr = 0; h = HH; mc = 0; w = WW_; }
            else {
                int rt2 = roots[slot];
                mr = minr[base + rt2];
                h  = maxr[base + rt2] + 1 - mr;
                mc = minc[base + rt2];
                w  = maxc[base + rt2] + 1 - mc;
            }
            int* o = bbox + (b * 3 + slot) * 4;
            o[0] = mr; o[1] = h; o[2] = mc; o[3] = w;
        }
    }
}

// ---------------------------------------------------------------------------
// Kernel 3: nearest-neighbor crop-resize gather. One float4 store per thread.
// out[b, slot*192+c, y, x] = feat[b, c, mr + (y*h)>>6, mc + (x*w)>>6]
// ---------------------------------------------------------------------------

__global__ __launch_bounds__(256) void crop_kernel(
    const float* __restrict__ feat, const int* __restrict__ bbox,
    float* __restrict__ out)
{
    const int gid = blockIdx.x * 256 + threadIdx.x;   // 9,437,184 total
    const int x4 = gid & 15;
    const int y  = (gid >> 4) & 63;
    const int t  = gid >> 10;        // (b*3+slot)*192 + c, 0..9215
    const int c  = t % CF;
    const int bs = t / CF;           // b*3+slot, 0..47
    const int* bb = bbox + bs * 4;
    const int mr = bb[0], h = bb[1], mc = bb[2], w = bb[3];
    const int r = mr + ((y * h) >> 6);
    const int bimg = bs / 3;
    const float* row = feat + (((size_t)bimg * CF + c) * HH + r) * WW_;
    const int x = x4 * 4;
    vf4 v;
    v.x = row[mc + (((x + 0) * w) >> 6)];
    v.y = row[mc + (((x + 1) * w) >> 6)];
    v.z = row[mc + (((x + 2) * w) >> 6)];
    v.w = row[mc + (((x + 3) * w) >> 6)];
    __builtin_nontemporal_store(v, (vf4*)out + gid);  // streaming store
}

// ---------------------------------------------------------------------------

extern "C" void kernel_launch(void* const* d_in, const int* in_sizes, int n_in,
                              void* d_out, int out_size, void* d_ws, size_t ws_size,
                              hipStream_t stream) {
    const float* prob = (const float*)d_in[0];   // [16,1,128,128]
    const float* feat = (const float*)d_in[1];   // [16,192,128,128]
    float* out = (float*)d_out;                  // [16,576,64,64]

    char* ws = (char*)d_ws;
    const size_t SEG = (size_t)NB * HW * 4;      // 1 MB per stats array
    int*   cnt      = (int*)(ws + 0 * SEG);
    float* conf     = (float*)(ws + 1 * SEG);
    int*   maxr     = (int*)(ws + 2 * SEG);
    int*   maxc     = (int*)(ws + 3 * SEG);
    int*   maxid    = (int*)(ws + 4 * SEG);
    int*   nroots   = (int*)(ws + 5 * SEG);             // 64 B
    int*   bbox     = (int*)(ws + 5 * SEG + 1024);      // 768 B
    int*   minr     = (int*)(ws + 5 * SEG + 4096);
    int*   minc     = (int*)(ws + 6 * SEG + 4096);
    int*   rootlist = (int*)(ws + 7 * SEG + 4096);      // 256 KB

    hipLaunchKernelGGL(ccl_stats_kernel, dim3(NB), dim3(1024), 0, stream,
                       prob, cnt, conf, maxr, maxc, maxid, minr, minc,
                       nroots, rootlist);
    hipLaunchKernelGGL(select_kernel, dim3(NB), dim3(256), 0, stream,
                       cnt, conf, maxr, maxc, maxid, minr, minc,
                       nroots, rootlist, bbox);
    const int total4 = NB * 3 * CF * H2 * (W2 / 4);   // 9,437,184
    hipLaunchKernelGGL(crop_kernel, dim3(total4 / 256), dim3(256), 0, stream,
                       feat, bbox, out);
}

// Round 4
// 386.443 us; speedup vs baseline: 1.3520x; 1.3520x over previous
//
#include <hip/hip_runtime.h>
#include <limits.h>

#define HH 128
#define WW_ 128
#define HW 16384
#define NB 16
#define CF 192
#define H2 64
#define W2 64
#define NRUN 8192     // max runs: 128 rows * 64 runs/row
#define NCOMP 4096    // max 8-connected components in 128x128

typedef float vf4 __attribute__((ext_vector_type(4)));
typedef unsigned long long ull;

// ---------------------------------------------------------------------------
// Union-find on LDS parent array indexed by run id = (row<<6) | runIdxInRow.
// Links always go high->low id -> chains strictly decrease -> concurrent
// path halving is safe and terminating.
// ---------------------------------------------------------------------------

__device__ inline int uf_find(int* par, int x) {
    volatile int* vp = (volatile int*)par;
    int p = vp[x];
    while (p != x) {
        int g = vp[p];
        vp[x] = g;      // path halving: writes an ancestor, safe under races
        x = g;
        p = vp[x];
    }
    return x;
}

__device__ inline void uf_union(int* par, int a, int b) {
    int ra = uf_find(par, a);
    int rb = uf_find(par, b);
    while (ra != rb) {
        if (ra < rb) { int t = ra; ra = rb; rb = t; }   // link larger -> smaller
        int old = atomicCAS(&par[ra], ra, rb);
        if (old == ra) return;
        ra = uf_find(par, old);
        rb = uf_find(par, rb);
    }
}

// ---------------------------------------------------------------------------
// 128-bit row mask helpers (lo = cols 0..63, hi = cols 64..127)
// ---------------------------------------------------------------------------

__device__ inline int getbit2(ull lo, ull hi, int c) {
    return (int)(((c < 64) ? (lo >> c) : (hi >> (c - 64))) & 1ULL);
}

__device__ inline int leading_ones(ull v) {
    ull nv = ~v;
    return (nv == 0ULL) ? 64 : __clzll(nv);
}

__device__ inline int trailing_ones(ull v) {
    ull nv = ~v;
    return (nv == 0ULL) ? 64 : (__ffsll(nv) - 1);
}

// column of the start of the fg run containing column c (bit c must be set)
__device__ inline int run_start_col(ull lo, ull hi, int c) {
    if (c < 64) {
        int ones = leading_ones(lo << (63 - c));   // consecutive ones ending at c
        return c - ones + 1;
    }
    int ones = leading_ones(hi << (127 - c));
    int rs = c - ones + 1;
    if (rs == 64) rs -= leading_ones(lo);          // run crosses the 64 boundary
    return rs;
}

// column of the end of the fg run containing column c (bit c must be set)
__device__ inline int run_end_col(ull lo, ull hi, int c) {
    if (c >= 64) {
        return c + trailing_ones(hi >> (c - 64)) - 1;
    }
    int e = c + trailing_ones(lo >> c) - 1;
    if (e == 63) e += trailing_ones(hi);           // run crosses the 64 boundary
    return e;
}

// 0-based index of the run starting at column cs (cs must be a run start)
__device__ inline int run_index(ull rs_lo, ull rs_hi, int cs) {
    if (cs < 64)  return __popcll(rs_lo & ((1ULL << cs) - 1ULL));
    if (cs == 64) return __popcll(rs_lo);
    return __popcll(rs_lo) + __popcll(rs_hi & ((1ULL << (cs - 64)) - 1ULL));
}

__device__ inline void top3_ins(float s, int id, int x,
    float& s0, float& s1, float& s2,
    int& i0, int& i1, int& i2,
    int& x0, int& x1, int& x2)
{
    if (x < 0) return;
    if (s > s0 || (s == s0 && id < i0)) {
        s2 = s1; i2 = i1; x2 = x1;
        s1 = s0; i1 = i0; x1 = x0;
        s0 = s;  i0 = id; x0 = x;
    } else if (s > s1 || (s == s1 && id < i1)) {
        s2 = s1; i2 = i1; x2 = x1;
        s1 = s;  i1 = id; x1 = x;
    } else if (s > s2 || (s == s2 && id < i2)) {
        s2 = s;  i2 = id; x2 = x;
    }
}

// ---------------------------------------------------------------------------
// Kernel 1: one block per image. Run-based union-find CCL + per-component
// stats + top-3 selection + bbox — ALL in LDS. Zero global atomics (the
// R1-R3 bottleneck: ~450k atomic RMWs write through to HBM at ~75 GB/s).
// Only global output: 3 bboxes per image.
// ---------------------------------------------------------------------------

__global__ __launch_bounds__(1024) void ccl_kernel(
    const float* __restrict__ prob, int* __restrict__ bbox)
{
    __shared__ int parent[NRUN];          // 32 KB
    __shared__ ull rowmask[HH][2];        // 2 KB
    __shared__ int   lcnt[NCOMP];         // 16 KB
    __shared__ float lconf[NCOMP];        // 16 KB
    __shared__ int lminr[NCOMP], lmaxr[NCOMP];
    __shared__ int lminc[NCOMP], lmaxc[NCOMP];
    __shared__ int lmaxid[NCOMP];         // 5 x 16 KB
    __shared__ int snroots;
    __shared__ float wss[48];
    __shared__ int wid_[48], wrx[48];

    const int b = blockIdx.x;
    const int tid = threadIdx.x;
    const float* p = prob + (size_t)b * HW;

    if (tid == 0) snroots = 0;

    // P0: per-row fg bitmasks via ballot (each wave = half a row, coalesced)
    #pragma unroll
    for (int k = 0; k < HW / 1024; ++k) {
        int i = k * 1024 + tid;
        ull m = __ballot(p[i] > 0.5f);
        if ((tid & 63) == 0) rowmask[i >> 7][(i >> 6) & 1] = m;
    }
    // init LDS stats (not read until P4; no extra barrier needed)
    for (int j = tid; j < NCOMP; j += 1024) {
        lcnt[j] = 0; lconf[j] = 0.f;
        lminr[j] = INT_MAX; lmaxr[j] = -1;
        lminc[j] = INT_MAX; lmaxc[j] = -1;
        lmaxid[j] = 0;
    }
    __syncthreads();

    // P1: parent self-init over valid run-id space
    for (int rid = tid; rid < NRUN; rid += 1024) {
        int r = rid >> 6;
        ull lo = rowmask[r][0], hi = rowmask[r][1];
        ull rs_lo = lo & ~(lo << 1);
        ull rs_hi = hi & ~((hi << 1) | (lo >> 63));
        int nruns = __popcll(rs_lo) + __popcll(rs_hi);
        if ((rid & 63) < nruns) parent[rid] = rid;
    }
    __syncthreads();

    // P2: vertical unions, fired once per (run, upper-run) contact pair
    for (int k = 0; k < HW / 1024; ++k) {
        int i = k * 1024 + tid;
        int r = i >> 7, c = i & 127;
        if (r == 0) continue;
        ull lo = rowmask[r][0], hi = rowmask[r][1];
        if (!getbit2(lo, hi, c)) continue;
        ull ulo = rowmask[r - 1][0], uhi = rowmask[r - 1][1];
        int l  = (c > 0)   ? getbit2(lo, hi, c - 1) : 0;
        int rt = (c < 127) ? getbit2(lo, hi, c + 1) : 0;
        int up = getbit2(ulo, uhi, c);
        int ul = (c > 0)   ? getbit2(ulo, uhi, c - 1) : 0;
        int ur = (c < 127) ? getbit2(ulo, uhi, c + 1) : 0;
        bool u1 = up && !(l && ul);          // leftmost-contact dedup
        bool u2 = !up && ul && !l;
        bool u3 = !up && ur && !rt;
        if (!(u1 | u2 | u3)) continue;
        ull rs_lo = lo & ~(lo << 1),   rs_hi = hi & ~((hi << 1) | (lo >> 63));
        ull urs_lo = ulo & ~(ulo << 1), urs_hi = uhi & ~((uhi << 1) | (ulo >> 63));
        int cs = run_start_col(lo, hi, c);
        int rid = (r << 6) + run_index(rs_lo, rs_hi, cs);
        int ub = (r - 1) << 6;
        if (u1) uf_union(parent, rid, ub + run_index(urs_lo, urs_hi, run_start_col(ulo, uhi, c)));
        if (u2) uf_union(parent, rid, ub + run_index(urs_lo, urs_hi, run_start_col(ulo, uhi, c - 1)));
        if (u3) uf_union(parent, rid, ub + run_index(urs_lo, urs_hi, run_start_col(ulo, uhi, c + 1)));
    }
    __syncthreads();

    // P3: flatten all runs to their root
    for (int rid = tid; rid < NRUN; rid += 1024) {
        int r = rid >> 6;
        ull lo = rowmask[r][0], hi = rowmask[r][1];
        ull rs_lo = lo & ~(lo << 1);
        ull rs_hi = hi & ~((hi << 1) | (lo >> 63));
        int nruns = __popcll(rs_lo) + __popcll(rs_hi);
        if ((rid & 63) < nruns) parent[rid] = uf_find(parent, rid);
    }
    __syncthreads();
    // P3b: roots claim dense indices; parent[root] = NRUN + denseIdx
    for (int rid = tid; rid < NRUN; rid += 1024) {
        int r = rid >> 6;
        ull lo = rowmask[r][0], hi = rowmask[r][1];
        ull rs_lo = lo & ~(lo << 1);
        ull rs_hi = hi & ~((hi << 1) | (lo >> 63));
        int nruns = __popcll(rs_lo) + __popcll(rs_hi);
        if ((rid & 63) < nruns && parent[rid] == rid) {
            int idx = atomicAdd(&snroots, 1);
            parent[rid] = NRUN + idx;
        }
    }
    __syncthreads();

    // P4: per-run stats into LDS dense arrays, with per-thread run
    // aggregation (thread = one 16-col window of one row)
    {
        int row = tid >> 3;
        int w0 = (tid & 7) * 16;
        ull lo = rowmask[row][0], hi = rowmask[row][1];
        ull rs_lo = lo & ~(lo << 1);
        ull rs_hi = hi & ~((hi << 1) | (lo >> 63));
        ull seg = ((w0 < 64) ? (rs_lo >> w0) : (rs_hi >> (w0 - 64))) & 0xFFFFULL;
        int curIdx = -1, aCnt = 0, aMinc = 0, aMaxc = 0, aMaxid = 0;
        float aConf = 0.f;
        while (seg) {
            int c = w0 + (__ffsll(seg) - 1);
            seg &= seg - 1;
            int e = run_end_col(lo, hi, c);
            int rid = (row << 6) + run_index(rs_lo, rs_hi, c);
            int v = parent[rid];
            int idx = (v >= NRUN) ? (v - NRUN) : (parent[v] - NRUN);
            float s = 0.f;
            for (int j = c; j <= e; ++j) s += p[(row << 7) + j];
            if (idx == curIdx) {
                aCnt += e - c + 1; aConf += s;
                aMaxc = e; aMaxid = (row << 7) + e + 1;
            } else {
                if (curIdx >= 0) {
                    atomicAdd(&lcnt[curIdx], aCnt);
                    atomicAdd(&lconf[curIdx], aConf);
                    atomicMin(&lminr[curIdx], row);
                    atomicMax(&lmaxr[curIdx], row);
                    atomicMin(&lminc[curIdx], aMinc);
                    atomicMax(&lmaxc[curIdx], aMaxc);
                    atomicMax(&lmaxid[curIdx], aMaxid);
                }
                curIdx = idx; aCnt = e - c + 1; aConf = s;
                aMinc = c; aMaxc = e; aMaxid = (row << 7) + e + 1;
            }
        }
        if (curIdx >= 0) {
            atomicAdd(&lcnt[curIdx], aCnt);
            atomicAdd(&lconf[curIdx], aConf);
            atomicMin(&lminr[curIdx], row);
            atomicMax(&lmaxr[curIdx], row);
            atomicMin(&lminc[curIdx], aMinc);
            atomicMax(&lmaxc[curIdx], aMaxc);
            atomicMax(&lmaxid[curIdx], aMaxid);
        }
    }
    __syncthreads();

    // P5: top-3 by (mean_conf desc, segment-id asc) — thread scan, wave
    // shfl_xor butterfly merge, tid0 final merge + K rules + bbox write
    const int n = snroots;
    float s0 = -INFINITY, s1 = -INFINITY, s2 = -INFINITY;
    int i0 = INT_MAX, i1 = INT_MAX, i2 = INT_MAX;
    int x0 = -1, x1 = -1, x2 = -1;
    for (int j = tid; j < n; j += 1024) {
        float s = lconf[j] / (float)lcnt[j];
        top3_ins(s, lmaxid[j], j, s0, s1, s2, i0, i1, i2, x0, x1, x2);
    }
    for (int off = 32; off; off >>= 1) {
        float bs0 = __shfl_xor(s0, off), bs1 = __shfl_xor(s1, off), bs2 = __shfl_xor(s2, off);
        int bi0 = __shfl_xor(i0, off), bi1 = __shfl_xor(i1, off), bi2 = __shfl_xor(i2, off);
        int bx0 = __shfl_xor(x0, off), bx1 = __shfl_xor(x1, off), bx2 = __shfl_xor(x2, off);
        top3_ins(bs0, bi0, bx0, s0, s1, s2, i0, i1, i2, x0, x1, x2);
        top3_ins(bs1, bi1, bx1, s0, s1, s2, i0, i1, i2, x0, x1, x2);
        top3_ins(bs2, bi2, bx2, s0, s1, s2, i0, i1, i2, x0, x1, x2);
    }
    if ((tid & 63) == 0) {
        int w = tid >> 6;
        wss[w * 3 + 0] = s0; wid_[w * 3 + 0] = i0; wrx[w * 3 + 0] = x0;
        wss[w * 3 + 1] = s1; wid_[w * 3 + 1] = i1; wrx[w * 3 + 1] = x1;
        wss[w * 3 + 2] = s2; wid_[w * 3 + 2] = i2; wrx[w * 3 + 2] = x2;
    }
    __syncthreads();

    if (tid == 0) {
        float t0 = -INFINITY, t1 = -INFINITY, t2 = -INFINITY;
        int ti0 = INT_MAX, ti1 = INT_MAX, ti2 = INT_MAX;
        int tx0 = -1, tx1 = -1, tx2 = -1;
        for (int t = 0; t < 48; ++t)
            top3_ins(wss[t], wid_[t], wrx[t], t0, t1, t2, ti0, ti1, ti2, tx0, tx1, tx2);
        int K = n;
        int roots[3];
        if (K >= 3)      { roots[0] = tx0; roots[1] = tx1; roots[2] = tx2; }
        else if (K == 2) { roots[0] = tx0; roots[1] = tx0; roots[2] = tx1; }
        else             { roots[0] = tx0; roots[1] = tx0; roots[2] = tx0; }
        for (int slot = 0; slot < 3; ++slot) {
            int mr, h, mc, w;
            if (K == 0) { mr = 0; h = HH; mc = 0; w = WW_; }
            else {
                int rt = roots[slot];
                mr = lminr[rt]; h = lmaxr[rt] + 1 - mr;
                mc = lminc[rt]; w = lmaxc[rt] + 1 - mc;
            }
            int* o = bbox + (b * 3 + slot) * 4;
            o[0] = mr; o[1] = h; o[2] = mc; o[3] = w;
        }
    }
}

// ---------------------------------------------------------------------------
// Kernel 2: nearest-neighbor crop-resize gather. One float4 store per thread.
// out[b, slot*192+c, y, x] = feat[b, c, mr + (y*h)>>6, mc + (x*w)>>6]
// ---------------------------------------------------------------------------

__global__ __launch_bounds__(256) void crop_kernel(
    const float* __restrict__ feat, const int* __restrict__ bbox,
    float* __restrict__ out)
{
    const int gid = blockIdx.x * 256 + threadIdx.x;   // 9,437,184 total
    const int x4 = gid & 15;
    const int y  = (gid >> 4) & 63;
    const int t  = gid >> 10;        // (b*3+slot)*192 + c, 0..9215
    const int c  = t % CF;
    const int bs = t / CF;           // b*3+slot, 0..47
    const int* bb = bbox + bs * 4;
    const int mr = bb[0], h = bb[1], mc = bb[2], w = bb[3];
    const int r = mr + ((y * h) >> 6);
    const int bimg = bs / 3;
    const float* row = feat + (((size_t)bimg * CF + c) * HH + r) * WW_;
    const int x = x4 * 4;
    vf4 v;
    v.x = row[mc + (((x + 0) * w) >> 6)];
    v.y = row[mc + (((x + 1) * w) >> 6)];
    v.z = row[mc + (((x + 2) * w) >> 6)];
    v.w = row[mc + (((x + 3) * w) >> 6)];
    __builtin_nontemporal_store(v, (vf4*)out + gid);  // streaming store
}

// ---------------------------------------------------------------------------

extern "C" void kernel_launch(void* const* d_in, const int* in_sizes, int n_in,
                              void* d_out, int out_size, void* d_ws, size_t ws_size,
                              hipStream_t stream) {
    const float* prob = (const float*)d_in[0];   // [16,1,128,128]
    const float* feat = (const float*)d_in[1];   // [16,192,128,128]
    float* out = (float*)d_out;                  // [16,576,64,64]

    int* bbox = (int*)d_ws;                      // [16][3][4] ints, fully written

    hipLaunchKernelGGL(ccl_kernel, dim3(NB), dim3(1024), 0, stream,
                       prob, bbox);
    const int total4 = NB * 3 * CF * H2 * (W2 / 4);   // 9,437,184
    hipLaunchKernelGGL(crop_kernel, dim3(total4 / 256), dim3(256), 0, stream,
                       feat, bbox, out);
}